// Round 1
// baseline (484.598 us; speedup 1.0000x reference)
//
#include <hip/hip_runtime.h>

#define T 15
#define HIN 256
#define C1N 32
#define C2N 150
#define PP 129          // pooled spatial
#define PADP 131        // padded pooled
#define HO 130          // conv2 output spatial
#define POS2 (HO*HO)    // 16900
#define NPOT2 (T*C2N*POS2)  // 38,025,000

// ---------------------------------------------------------------- k0: first-spike time per input pixel
__global__ void k_tfirst(const float* __restrict__ in, int* __restrict__ tf) {
  int i = blockIdx.x * 256 + threadIdx.x;
  if (i >= 2 * HIN * HIN) return;
  float s = 0.f;
#pragma unroll
  for (int t = 0; t < T; t++) s += in[t * (2 * HIN * HIN) + i];
  tf[i] = T - (int)(s + 0.5f);   // input is cumulative binary: sum = #active steps
}

// ---------------------------------------------------------------- k1: conv1 + fire(10) + maxpool(2,2,p1) -> 15-bit masks
__global__ void __launch_bounds__(256) k_conv1_pool(const int* __restrict__ tf,
                                                    const float* __restrict__ w1,
                                                    unsigned* __restrict__ pb) {
  int i = blockIdx.x * 256 + threadIdx.x;
  if (i >= C1N * PP * PP) return;
  int pw = i % PP, ph = (i / PP) % PP, c = i / (PP * PP);
  float wr[50];
#pragma unroll
  for (int j = 0; j < 50; j++) wr[j] = w1[c * 50 + j];
  unsigned bits = 0;
#pragma unroll
  for (int pp = 0; pp < 4; pp++) {
    int h = 2 * ph - 1 + (pp >> 1);
    int w = 2 * pw - 1 + (pp & 1);
    if (h < 0 || h >= HIN || w < 0 || w >= HIN) continue;
    float pot[T];
#pragma unroll
    for (int t = 0; t < T; t++) pot[t] = 0.f;
    // accumulation order (kh, kw, ci) with ci innermost — XLA:CPU/Eigen NHWC order
#pragma unroll
    for (int kh = 0; kh < 5; kh++) {
      int hh = h + kh - 2;
#pragma unroll
      for (int kw = 0; kw < 5; kw++) {
        int ww = w + kw - 2;
        bool inb = (hh >= 0 && hh < HIN && ww >= 0 && ww < HIN);
#pragma unroll
        for (int ci = 0; ci < 2; ci++) {
          int t0 = inb ? tf[ci * HIN * HIN + hh * HIN + ww] : T;
          float wv = wr[(ci * 5 + kh) * 5 + kw];
#pragma unroll
          for (int t = 0; t < T; t++) pot[t] += (t >= t0) ? wv : 0.f;
        }
      }
    }
#pragma unroll
    for (int t = 0; t < T; t++) if (pot[t] > 10.0f) bits |= (1u << t);
  }
  pb[i] = bits;
}

// ---------------------------------------------------------------- k2: pointwise inhibition on padded pooled spikes
// output packed[h*131+w]: bits0-14 = winner spike train, bits16+ = winner_channel+1 (0 => no winner)
__global__ void k_inhib1(const unsigned* __restrict__ pb, unsigned* __restrict__ packed) {
  int i = blockIdx.x * 256 + threadIdx.x;
  if (i >= PADP * PADP) return;
  int wp = i % PADP, hp = i / PADP;
  if (hp == 0 || hp == PADP - 1 || wp == 0 || wp == PADP - 1) { packed[i] = 0; return; }
  int ph = hp - 1, pw = wp - 1;
  unsigned seen = 0;
  int fc[T];
#pragma unroll
  for (int t = 0; t < T; t++) fc[t] = 0;   // argmax of all-zeros is channel 0 (ref semantics)
  for (int c = 0; c < C1N; c++) {
    unsigned b = pb[(c * PP + ph) * PP + pw] & 0x7FFFu;
    unsigned nb = b & ~seen;
    if (nb) {
#pragma unroll
      for (int t = 0; t < T; t++) if ((nb >> t) & 1u) fc[t] = c;
    }
    seen |= b;
  }
  int cnt = __popc(seen);
  int spiked = (seen >> (T - 1)) & 1u;
  int e = T - cnt; e = e < 0 ? 0 : (e > T - 1 ? T - 1 : e);
  int win = 0;
#pragma unroll
  for (int t = 0; t < T; t++) win = (t == e) ? fc[t] : win;
  unsigned res = 0;
  if (spiked) {
    unsigned wb = pb[(win * PP + ph) * PP + pw] & 0x7FFFu;
    res = wb | ((unsigned)(win + 1) << 16);
  }
  packed[i] = res;
}

// ---------------------------------------------------------------- k3: conv2 (<=4 terms) + fire(1.0) -> pot2 (d_out chunk 0)
__global__ void __launch_bounds__(256) k_conv2(const unsigned* __restrict__ packed,
                                               const float* __restrict__ w2,
                                               float* __restrict__ pot2) {
  int i = blockIdx.x * 256 + threadIdx.x;
  if (i >= NPOT2) return;
  int w = i % HO;
  int h = (i / HO) % HO;
  int f = (i / POS2) % C2N;
  int t = i / (C2N * POS2);
  float s = 0.f;
#pragma unroll
  for (int p = 0; p < 4; p++) {           // (kh,kw) order = canonical reduction order
    int kh = p >> 1, kw = p & 1;
    unsigned pk = packed[(h + kh) * PADP + (w + kw)];
    int c = (int)(pk >> 16) - 1;
    float wv = (c >= 0) ? w2[((f * C1N + c) * 2 + kh) * 2 + kw] : 0.f;
    s += ((pk >> t) & 1u) ? wv : 0.f;
  }
  pot2[i] = (s > 1.0f) ? s : 0.f;
}

// ---------------------------------------------------------------- k4: pointwise inhibition on pot2 (in-place) + k-winner stats
__global__ void __launch_bounds__(192) k_inhib2(float* __restrict__ pot2,
                                                int* __restrict__ win2,
                                                float* __restrict__ val2,
                                                int* __restrict__ nspk2) {
  int h = blockIdx.x;
  int w = threadIdx.x;
  if (w >= HO) return;
  float mx[T]; int mi[T];
#pragma unroll
  for (int t = 0; t < T; t++) { mx[t] = -1.f; mi[t] = 0; }
  for (int c = 0; c < C2N; c++) {
#pragma unroll
    for (int t = 0; t < T; t++) {
      float v = pot2[(t * C2N + c) * POS2 + h * HO + w];
      if (v > mx[t]) { mx[t] = v; mi[t] = c; }   // strict > keeps first (lowest c) on ties
    }
  }
  int cnt = 0;
#pragma unroll
  for (int t = 0; t < T; t++) cnt += (mx[t] > 0.f) ? 1 : 0;
  int spiked = (mx[T - 1] > 0.f) ? 1 : 0;
  int e = T - cnt; e = e < 0 ? 0 : (e > T - 1 ? T - 1 : e);
  int win = 0;
#pragma unroll
  for (int t = 0; t < T; t++) win = (t == e) ? mi[t] : win;
  if (!spiked) win = -1;
  // stats for get_k_winners from the (post-inhibition) winner channel
  float pv[T];
#pragma unroll
  for (int t = 0; t < T; t++) pv[t] = (win >= 0) ? pot2[(t * C2N + win) * POS2 + h * HO + w] : 0.f;
  int n = 0;
#pragma unroll
  for (int t = 0; t < T; t++) n += (pv[t] > 0.f) ? 1 : 0;
  int e2 = T - n; e2 = e2 < 0 ? 0 : (e2 > T - 1 ? T - 1 : e2);
  float vv = 0.f;
#pragma unroll
  for (int t = 0; t < T; t++) vv = (t == e2) ? pv[t] : vv;
  int pos = h * HO + w;
  win2[pos] = win; val2[pos] = vv; nspk2[pos] = n;
  // zero all losing channels (all channels if win == -1)
  for (int c = 0; c < C2N; c++) {
    bool keep = (c == win);
#pragma unroll
    for (int t = 0; t < T; t++) {
      if (!keep) pot2[(t * C2N + c) * POS2 + pos] = 0.f;
    }
  }
}

// ---------------------------------------------------------------- k5: get_k_winners (single block, compact per-position rep)
__global__ void __launch_bounds__(1024) k_kwin(const int* __restrict__ win2,
                                               const float* __restrict__ val2,
                                               const int* __restrict__ nspk2,
                                               float* __restrict__ wout) {
  const int NE = 17;  // ceil(16900/1024)
  int tid = threadIdx.x;
  float tot[NE]; int wch[NE]; float vr[NE]; int nr[NE];
  float vmax = 0.f;
#pragma unroll
  for (int j = 0; j < NE; j++) {
    int i = tid + j * 1024;
    bool ok = (i < POS2);
    wch[j] = ok ? win2[i] : -1;
    vr[j]  = ok ? val2[i] : 0.f;
    nr[j]  = ok ? nspk2[i] : 0;
    if (nr[j] > 0 && vr[j] > vmax) vmax = vr[j];
  }
  __shared__ float sv[1024];
  __shared__ int   si[1024];
  __shared__ float swin[24];
  sv[tid] = vmax; __syncthreads();
  for (int s = 512; s > 0; s >>= 1) { if (tid < s) sv[tid] = fmaxf(sv[tid], sv[tid + s]); __syncthreads(); }
  float v = sv[0] * 15.f;              // v = trunc.max() * T
  __syncthreads();
#pragma unroll
  for (int j = 0; j < NE; j++) tot[j] = (float)nr[j] * (vr[j] + v);

  for (int k = 0; k < 8; k++) {
    float bm = 0.f; int bi = 0x7FFFFFFF;
#pragma unroll
    for (int j = 0; j < NE; j++) {
      int i = tid + j * 1024;
      int fl = wch[j] * POS2 + i;       // reference flat index c*16900 + h*130 + w
      bool better = (tot[j] > bm) || (tot[j] == bm && fl < bi);
      if (better) { bm = tot[j]; bi = fl; }
    }
    sv[tid] = bm; si[tid] = bi; __syncthreads();
    for (int s = 512; s > 0; s >>= 1) {
      if (tid < s) {
        float ov = sv[tid + s]; int oi = si[tid + s];
        if (ov > sv[tid] || (ov == sv[tid] && oi < si[tid])) { sv[tid] = ov; si[tid] = oi; }
      }
      __syncthreads();
    }
    float mval = sv[0]; int midx = si[0];
    __syncthreads();
    int c = midx / POS2, pos = midx % POS2, r = pos / HO, q = pos % HO;
    if (tid == 0) {
      if (mval != 0.f) { swin[k*3] = (float)c; swin[k*3+1] = (float)r; swin[k*3+2] = (float)q; }
      else             { swin[k*3] = -1.f;     swin[k*3+1] = -1.f;     swin[k*3+2] = -1.f;     }
    }
    if (mval != 0.f) {
#pragma unroll
      for (int j = 0; j < NE; j++) {
        int i = tid + j * 1024;
        int hh = i / HO, ww = i % HO;
        bool kill = (wch[j] == c) || (hh >= r - 1 && hh <= r + 1 && ww >= q - 1 && ww <= q + 1);
        if (kill) tot[j] = 0.f;
      }
    }
    __syncthreads();
  }
  if (tid < 24) wout[tid] = swin[tid];
}

// ---------------------------------------------------------------- k6: spk2 = sign(pot2); overwrites all scratch in chunk 1
__global__ void k_sign(const float4* __restrict__ p, float4* __restrict__ s) {
  int i = blockIdx.x * 256 + threadIdx.x;
  if (i >= NPOT2 / 4) return;
  float4 vv = p[i];
  float4 o;
  o.x = vv.x > 0.f ? 1.f : 0.f;
  o.y = vv.y > 0.f ? 1.f : 0.f;
  o.z = vv.z > 0.f ? 1.f : 0.f;
  o.w = vv.w > 0.f ? 1.f : 0.f;
  s[i] = o;
}

extern "C" void kernel_launch(void* const* d_in, const int* in_sizes, int n_in,
                              void* d_out, int out_size, void* d_ws, size_t ws_size,
                              hipStream_t stream) {
  const float* in = (const float*)d_in[0];
  const float* w1 = (const float*)d_in[1];
  const float* w2 = (const float*)d_in[2];
  (void)d_ws; (void)ws_size; (void)in_sizes; (void)n_in; (void)out_size;

  float* pot2 = (float*)d_out;            // chunk 0: [15,150,130,130]
  float* spk2 = pot2 + NPOT2;             // chunk 1: [15,150,130,130] (also scratch until k_sign)
  float* wout = pot2 + 2 * (long long)NPOT2;  // chunk 2: [8,3]

  // scratch inside spk2 chunk (all consumed before k_sign overwrites it)
  float* scr = spk2;
  int*      tf     = (int*)     (scr + 0);        // 131072 ints
  unsigned* pb     = (unsigned*)(scr + 131072);   // 532512 uints
  unsigned* packed = (unsigned*)(scr + 663584);   // 17161 uints
  int*      win2   = (int*)     (scr + 680745);   // 16900 ints
  float*    val2   = (float*)   (scr + 697645);   // 16900 floats
  int*      nspk2  = (int*)     (scr + 714545);   // 16900 ints

  hipLaunchKernelGGL(k_tfirst, dim3((2 * HIN * HIN + 255) / 256), dim3(256), 0, stream, in, tf);
  hipLaunchKernelGGL(k_conv1_pool, dim3((C1N * PP * PP + 255) / 256), dim3(256), 0, stream, tf, w1, pb);
  hipLaunchKernelGGL(k_inhib1, dim3((PADP * PADP + 255) / 256), dim3(256), 0, stream, pb, packed);
  hipLaunchKernelGGL(k_conv2, dim3((NPOT2 + 255) / 256), dim3(256), 0, stream, packed, w2, pot2);
  hipLaunchKernelGGL(k_inhib2, dim3(HO), dim3(192), 0, stream, pot2, win2, val2, nspk2);
  hipLaunchKernelGGL(k_kwin, dim3(1), dim3(1024), 0, stream, win2, val2, nspk2, wout);
  hipLaunchKernelGGL(k_sign, dim3((NPOT2 / 4 + 255) / 256), dim3(256), 0, stream,
                     (const float4*)pot2, (float4*)spk2);
}

// Round 2
// 265.444 us; speedup vs baseline: 1.8256x; 1.8256x over previous
//
#include <hip/hip_runtime.h>

#define T 15
#define HIN 256
#define C1N 32
#define C2N 150
#define CHW 256              // conv1 output spatial
#define PP 129               // pooled spatial
#define PADP 131             // padded pooled
#define HO 130               // conv2 output spatial
#define POS2 (HO*HO)         // 16900
#define POS4 (POS2/4)        // 4225
#define NPOT2 (T*C2N*POS2)   // 38,025,000

// ---------------------------------------------------------------- k0: first-spike time per input pixel
__global__ void k_tfirst(const float* __restrict__ in, int* __restrict__ tf) {
  int i = blockIdx.x * 256 + threadIdx.x;
  if (i >= 2 * HIN * HIN) return;
  float s = 0.f;
#pragma unroll
  for (int t = 0; t < T; t++) s += in[t * (2 * HIN * HIN) + i];
  tf[i] = T - (int)(s + 0.5f);   // cumulative binary input: sum = #active steps
}

// ---------------------------------------------------------------- k1: conv1 + fire(10) via monotone binary search -> 15-bit masks per conv position
__global__ void __launch_bounds__(256) k_conv1(const int* __restrict__ tf,
                                               const float* __restrict__ w1,
                                               unsigned* __restrict__ pbf) {
  int i = blockIdx.x * 256 + threadIdx.x;
  if (i >= C1N * CHW * CHW) return;
  int w = i & 255, h = (i >> 8) & 255, c = i >> 16;
  float wr[50]; int t0[50];
  // tap order (kh, kw, ci) — matches the round-1 validated accumulation order
#pragma unroll
  for (int kh = 0; kh < 5; kh++) {
    int hh = h + kh - 2;
#pragma unroll
    for (int kw = 0; kw < 5; kw++) {
      int ww = w + kw - 2;
      bool inb = (hh >= 0 && hh < HIN && ww >= 0 && ww < HIN);
#pragma unroll
      for (int ci = 0; ci < 2; ci++) {
        int q = (kh * 5 + kw) * 2 + ci;
        wr[q] = w1[c * 50 + ci * 25 + kh * 5 + kw];
        t0[q] = inb ? tf[ci * HIN * HIN + hh * HIN + ww] : T;
      }
    }
  }
  auto ev = [&](int tc) -> float {
    float s = 0.f;
#pragma unroll
    for (int q = 0; q < 50; q++) s += (t0[q] <= tc) ? wr[q] : 0.f;
    return s;
  };
  // first t in [0,15] with pot(t) > 10 (15 = never); pot monotone since w > 0
  int t = 0;
  if (!(ev(t + 7) > 10.0f)) t += 8;
  if (!(ev(t + 3) > 10.0f)) t += 4;
  if (!(ev(t + 1) > 10.0f)) t += 2;
  if (!(ev(t)     > 10.0f)) t += 1;
  pbf[i] = (unsigned)((0x7FFF << t) & 0x7FFF);
}

// ---------------------------------------------------------------- k2: maxpool(2,2,p1) = OR of spike masks
__global__ void k_pool(const unsigned* __restrict__ pbf, unsigned* __restrict__ pb) {
  int i = blockIdx.x * 256 + threadIdx.x;
  if (i >= C1N * PP * PP) return;
  int pw = i % PP, ph = (i / PP) % PP, c = i / (PP * PP);
  int h0 = 2 * ph - 1, w0 = 2 * pw - 1;
  unsigned b = 0;
#pragma unroll
  for (int p = 0; p < 4; p++) {
    int h = h0 + (p >> 1), w = w0 + (p & 1);
    if (h >= 0 && h < CHW && w >= 0 && w < CHW) b |= pbf[c * CHW * CHW + h * CHW + w];
  }
  pb[i] = b;
}

// ---------------------------------------------------------------- k3: pointwise inhibition on padded pooled spikes
// packed[h*131+w]: bits0-14 = winner spike train, bits16+ = winner_channel+1 (0 => no winner)
__global__ void k_inhib1(const unsigned* __restrict__ pb, unsigned* __restrict__ packed) {
  int i = blockIdx.x * 256 + threadIdx.x;
  if (i >= PADP * PADP) return;
  int wp = i % PADP, hp = i / PADP;
  if (hp == 0 || hp == PADP - 1 || wp == 0 || wp == PADP - 1) { packed[i] = 0; return; }
  int ph = hp - 1, pw = wp - 1;
  unsigned seen = 0;
  int fc[T];
#pragma unroll
  for (int t = 0; t < T; t++) fc[t] = 0;
  for (int c = 0; c < C1N; c++) {
    unsigned b = pb[(c * PP + ph) * PP + pw] & 0x7FFFu;
    unsigned nb = b & ~seen;
    if (nb) {
#pragma unroll
      for (int t = 0; t < T; t++) if ((nb >> t) & 1u) fc[t] = c;
    }
    seen |= b;
  }
  int cnt = __popc(seen);
  int spiked = (seen >> (T - 1)) & 1u;
  int e = T - cnt; e = e < 0 ? 0 : (e > T - 1 ? T - 1 : e);
  int win = 0;
#pragma unroll
  for (int t = 0; t < T; t++) win = (t == e) ? fc[t] : win;
  unsigned res = 0;
  if (spiked) {
    unsigned wb = pb[(win * PP + ph) * PP + pw] & 0x7FFFu;
    res = wb | ((unsigned)(win + 1) << 16);
  }
  packed[i] = res;
}

// ---------------------------------------------------------------- k4: per (t,pos): conv2 on the fly + fire(1) -> channel max/argmax
__global__ void __launch_bounds__(256) k_score(const unsigned* __restrict__ packed,
                                               const float* __restrict__ w2,
                                               float* __restrict__ mx, int* __restrict__ mi) {
  int i = blockIdx.x * 256 + threadIdx.x;
  if (i >= T * POS2) return;
  int pos = i % POS2, t = i / POS2;
  int h = pos / HO, w = pos % HO;
  unsigned pk0 = packed[h * PADP + w],       pk1 = packed[h * PADP + w + 1];
  unsigned pk2 = packed[(h + 1) * PADP + w], pk3 = packed[(h + 1) * PADP + w + 1];
  int c0 = (int)(pk0 >> 16) - 1, c1 = (int)(pk1 >> 16) - 1;
  int c2 = (int)(pk2 >> 16) - 1, c3 = (int)(pk3 >> 16) - 1;
  bool a0 = (c0 >= 0) && ((pk0 >> t) & 1u), a1 = (c1 >= 0) && ((pk1 >> t) & 1u);
  bool a2 = (c2 >= 0) && ((pk2 >> t) & 1u), a3 = (c3 >= 0) && ((pk3 >> t) & 1u);
  int o0 = (c0 >= 0 ? c0 : 0) * 4 + 0, o1 = (c1 >= 0 ? c1 : 0) * 4 + 1;
  int o2 = (c2 >= 0 ? c2 : 0) * 4 + 2, o3 = (c3 >= 0 ? c3 : 0) * 4 + 3;
  float bmx = -1.f; int bmi = 0;
  for (int f = 0; f < C2N; f++) {
    const float* wf = w2 + f * 128;
    float s = 0.f;                       // tap order p=0..3 = (kh,kw) — ref reduction order
    s += a0 ? wf[o0] : 0.f;
    s += a1 ? wf[o1] : 0.f;
    s += a2 ? wf[o2] : 0.f;
    s += a3 ? wf[o3] : 0.f;
    float v = (s > 1.0f) ? s : 0.f;
    if (v > bmx) { bmx = v; bmi = f; }   // strict > keeps first index on ties
  }
  mx[i] = bmx; mi[i] = bmi;
}

// ---------------------------------------------------------------- k5: per pos: winner channel + k-winner stats
__global__ void k_winpos(const float* __restrict__ mx, const int* __restrict__ mi,
                         const unsigned* __restrict__ packed, const float* __restrict__ w2,
                         int* __restrict__ win2, float* __restrict__ val2, int* __restrict__ nspk2) {
  int pos = blockIdx.x * 256 + threadIdx.x;
  if (pos >= POS2) return;
  float m[T]; int q[T];
#pragma unroll
  for (int t = 0; t < T; t++) { m[t] = mx[t * POS2 + pos]; q[t] = mi[t * POS2 + pos]; }
  int cnt = 0;
#pragma unroll
  for (int t = 0; t < T; t++) cnt += (m[t] > 0.f) ? 1 : 0;
  int spiked = (m[T - 1] > 0.f) ? 1 : 0;
  int e = T - cnt; e = e < 0 ? 0 : (e > T - 1 ? T - 1 : e);
  int win = 0;
#pragma unroll
  for (int t = 0; t < T; t++) win = (t == e) ? q[t] : win;
  if (!spiked) win = -1;

  int h = pos / HO, w = pos % HO;
  unsigned pk0 = packed[h * PADP + w],       pk1 = packed[h * PADP + w + 1];
  unsigned pk2 = packed[(h + 1) * PADP + w], pk3 = packed[(h + 1) * PADP + w + 1];
  int c0 = (int)(pk0 >> 16) - 1, c1 = (int)(pk1 >> 16) - 1;
  int c2 = (int)(pk2 >> 16) - 1, c3 = (int)(pk3 >> 16) - 1;
  float wv0 = 0.f, wv1 = 0.f, wv2 = 0.f, wv3 = 0.f;
  if (win >= 0) {
    const float* wf = w2 + win * 128;
    wv0 = (c0 >= 0) ? wf[c0 * 4 + 0] : 0.f;
    wv1 = (c1 >= 0) ? wf[c1 * 4 + 1] : 0.f;
    wv2 = (c2 >= 0) ? wf[c2 * 4 + 2] : 0.f;
    wv3 = (c3 >= 0) ? wf[c3 * 4 + 3] : 0.f;
  }
  float pv[T];
#pragma unroll
  for (int t = 0; t < T; t++) {
    float s = 0.f;
    s += ((pk0 >> t) & 1u) ? wv0 : 0.f;
    s += ((pk1 >> t) & 1u) ? wv1 : 0.f;
    s += ((pk2 >> t) & 1u) ? wv2 : 0.f;
    s += ((pk3 >> t) & 1u) ? wv3 : 0.f;
    pv[t] = (win >= 0 && s > 1.0f) ? s : 0.f;
  }
  int n = 0;
#pragma unroll
  for (int t = 0; t < T; t++) n += (pv[t] > 0.f) ? 1 : 0;
  int e2 = T - n; e2 = e2 < 0 ? 0 : (e2 > T - 1 ? T - 1 : e2);
  float vv = 0.f;
#pragma unroll
  for (int t = 0; t < T; t++) vv = (t == e2) ? pv[t] : vv;
  win2[pos] = win; val2[pos] = vv; nspk2[pos] = n;
}

// ---------------------------------------------------------------- k6: get_k_winners (single block, shfl-butterfly argmax)
__global__ void __launch_bounds__(1024) k_kwin(const int* __restrict__ win2,
                                               const float* __restrict__ val2,
                                               const int* __restrict__ nspk2,
                                               float* __restrict__ wout) {
  const int NE = 17;  // ceil(16900/1024)
  int tid = threadIdx.x;
  int lane = tid & 63, wid = tid >> 6;
  float tot[NE]; int wch[NE]; float vr[NE]; int nr[NE];
  float vmax = 0.f;
#pragma unroll
  for (int j = 0; j < NE; j++) {
    int i = tid + j * 1024;
    bool ok = (i < POS2);
    wch[j] = ok ? win2[i] : -1;
    vr[j]  = ok ? val2[i] : 0.f;
    nr[j]  = ok ? nspk2[i] : 0;
    if (nr[j] > 0 && vr[j] > vmax) vmax = vr[j];
  }
  __shared__ float sred[16];
  __shared__ float sbc[1];
  __shared__ float svv[16]; __shared__ int sii[16];
  __shared__ int sres[2];
  __shared__ float swin[24];
#pragma unroll
  for (int off = 32; off > 0; off >>= 1) vmax = fmaxf(vmax, __shfl_xor(vmax, off));
  if (lane == 0) sred[wid] = vmax;
  __syncthreads();
  if (tid == 0) {
    float mm = sred[0];
    for (int k = 1; k < 16; k++) mm = fmaxf(mm, sred[k]);
    sbc[0] = mm * 15.f;                  // v = trunc.max() * T
  }
  __syncthreads();
  float v = sbc[0];
#pragma unroll
  for (int j = 0; j < NE; j++) tot[j] = (float)nr[j] * (vr[j] + v);

  for (int k = 0; k < 8; k++) {
    float bm = 0.f; int bi = 0x7FFFFFFF;
#pragma unroll
    for (int j = 0; j < NE; j++) {
      int i = tid + j * 1024;
      int fl = wch[j] * POS2 + i;        // reference flat index c*16900 + h*130 + w
      bool better = (tot[j] > bm) || (tot[j] == bm && fl < bi);
      if (better) { bm = tot[j]; bi = fl; }
    }
#pragma unroll
    for (int off = 32; off > 0; off >>= 1) {
      float ov = __shfl_xor(bm, off); int oi = __shfl_xor(bi, off);
      if (ov > bm || (ov == bm && oi < bi)) { bm = ov; bi = oi; }
    }
    if (lane == 0) { svv[wid] = bm; sii[wid] = bi; }
    __syncthreads();
    if (tid == 0) {
      float mb = svv[0]; int mj = sii[0];
      for (int u = 1; u < 16; u++)
        if (svv[u] > mb || (svv[u] == mb && sii[u] < mj)) { mb = svv[u]; mj = sii[u]; }
      sres[0] = __float_as_int(mb); sres[1] = mj;
      int c = mj / POS2, pos = mj % POS2, r = pos / HO, qq = pos % HO;
      if (mb != 0.f) { swin[k*3] = (float)c; swin[k*3+1] = (float)r; swin[k*3+2] = (float)qq; }
      else           { swin[k*3] = -1.f;     swin[k*3+1] = -1.f;     swin[k*3+2] = -1.f;     }
    }
    __syncthreads();
    float mval = __int_as_float(sres[0]); int midx = sres[1];
    if (mval != 0.f) {
      int c = midx / POS2, pos = midx % POS2, r = pos / HO, qq = pos % HO;
#pragma unroll
      for (int j = 0; j < NE; j++) {
        int i = tid + j * 1024;
        int hh = i / HO, ww = i % HO;
        bool kill = (wch[j] == c) || (hh >= r - 1 && hh <= r + 1 && ww >= qq - 1 && ww <= qq + 1);
        if (kill) tot[j] = 0.f;
      }
    }
    __syncthreads();
  }
  if (tid < 24) wout[tid] = swin[tid];
}

// ---------------------------------------------------------------- k7: final writer — pot2 (winner-only recompute) + spk2, 304 MB
__global__ void __launch_bounds__(256) k_final(const unsigned* __restrict__ packed,
                                               const float* __restrict__ w2,
                                               const int* __restrict__ win2,
                                               float4* __restrict__ pot2, float4* __restrict__ spk2) {
  int i4 = blockIdx.x * 256 + threadIdx.x;
  if (i4 >= NPOT2 / 4) return;
  int p4 = i4 % POS4;
  int c  = (i4 / POS4) % C2N;
  int t  = i4 / (POS4 * C2N);
  int pos0 = p4 * 4;
  int4 wn4 = *reinterpret_cast<const int4*>(win2 + pos0);
  const int* wn = reinterpret_cast<const int*>(&wn4);
  float o[4], sp[4];
#pragma unroll
  for (int j = 0; j < 4; j++) {
    float val = 0.f;
    if (wn[j] == c) {
      int pos = pos0 + j;
      int h = pos / HO, w = pos % HO;
      unsigned pk0 = packed[h * PADP + w],       pk1 = packed[h * PADP + w + 1];
      unsigned pk2 = packed[(h + 1) * PADP + w], pk3 = packed[(h + 1) * PADP + w + 1];
      int c0 = (int)(pk0 >> 16) - 1, c1 = (int)(pk1 >> 16) - 1;
      int c2 = (int)(pk2 >> 16) - 1, c3 = (int)(pk3 >> 16) - 1;
      const float* wf = w2 + c * 128;
      float s = 0.f;
      s += ((c0 >= 0) && ((pk0 >> t) & 1u)) ? wf[(c0 >= 0 ? c0 : 0) * 4 + 0] : 0.f;
      s += ((c1 >= 0) && ((pk1 >> t) & 1u)) ? wf[(c1 >= 0 ? c1 : 0) * 4 + 1] : 0.f;
      s += ((c2 >= 0) && ((pk2 >> t) & 1u)) ? wf[(c2 >= 0 ? c2 : 0) * 4 + 2] : 0.f;
      s += ((c3 >= 0) && ((pk3 >> t) & 1u)) ? wf[(c3 >= 0 ? c3 : 0) * 4 + 3] : 0.f;
      val = (s > 1.0f) ? s : 0.f;
    }
    o[j] = val; sp[j] = (val > 0.f) ? 1.f : 0.f;
  }
  pot2[i4] = make_float4(o[0], o[1], o[2], o[3]);
  spk2[i4] = make_float4(sp[0], sp[1], sp[2], sp[3]);
}

extern "C" void kernel_launch(void* const* d_in, const int* in_sizes, int n_in,
                              void* d_out, int out_size, void* d_ws, size_t ws_size,
                              hipStream_t stream) {
  const float* in = (const float*)d_in[0];
  const float* w1 = (const float*)d_in[1];
  const float* w2 = (const float*)d_in[2];
  (void)in_sizes; (void)n_in; (void)out_size; (void)ws_size;

  float* pot2 = (float*)d_out;                    // chunk 0: [15,150,130,130]
  float* spk2 = pot2 + NPOT2;                     // chunk 1: [15,150,130,130]
  float* wout = pot2 + 2 * (size_t)NPOT2;         // chunk 2: [8,3]

  // small scratch that must survive until k_final -> d_ws (136 KB)
  unsigned* packed = (unsigned*)d_ws;             // 17161 u32
  int*      win2   = (int*)d_ws + 17164;          // 16900 i32, 16B-aligned offset

  // bulky early scratch lives in pot2 chunk (fully consumed before k_final overwrites)
  float* scr = pot2;
  int*      tf    = (int*)     (scr);             // 131072
  unsigned* pbf   = (unsigned*)(scr + 131072);    // 2097152
  unsigned* pb    = (unsigned*)(scr + 2228224);   // 532512
  float*    mx    = (float*)   (scr + 2760736);   // 253500
  int*      mi    = (int*)     (scr + 3014236);   // 253500
  float*    val2  = (float*)   (scr + 3267736);   // 16900
  int*      nspk2 = (int*)     (scr + 3284636);   // 16900

  hipLaunchKernelGGL(k_tfirst, dim3((2 * HIN * HIN + 255) / 256), dim3(256), 0, stream, in, tf);
  hipLaunchKernelGGL(k_conv1,  dim3((C1N * CHW * CHW + 255) / 256), dim3(256), 0, stream, tf, w1, pbf);
  hipLaunchKernelGGL(k_pool,   dim3((C1N * PP * PP + 255) / 256), dim3(256), 0, stream, pbf, pb);
  hipLaunchKernelGGL(k_inhib1, dim3((PADP * PADP + 255) / 256), dim3(256), 0, stream, pb, packed);
  hipLaunchKernelGGL(k_score,  dim3((T * POS2 + 255) / 256), dim3(256), 0, stream, packed, w2, mx, mi);
  hipLaunchKernelGGL(k_winpos, dim3((POS2 + 255) / 256), dim3(256), 0, stream, mx, mi, packed, w2, win2, val2, nspk2);
  hipLaunchKernelGGL(k_kwin,   dim3(1), dim3(1024), 0, stream, win2, val2, nspk2, wout);
  hipLaunchKernelGGL(k_final,  dim3((NPOT2 / 4 + 255) / 256), dim3(256), 0, stream,
                     packed, w2, win2, (float4*)pot2, (float4*)spk2);
}